// Round 1
// baseline (1594.866 us; speedup 1.0000x reference)
//
#include <hip/hip_runtime.h>
#include <math.h>

#define Bn 4
#define Cn 32
#define Dn 64
#define Hn 64
#define Wn 64
#define PLANE (Hn * Wn)    // 4096
#define DT 16              // d-planes per block
#define LSTRIDE 68         // padded row stride: 68*4 = 272 B (16B-aligned rows, +4-bank offset/row)
#define LROWS 66           // padded rows 0..65 hold data rows -1..64
#define LPLANE (LROWS * LSTRIDE)   // 4488 floats = 17952 B

// Exact-grade GELU: 0.5x(1+erf(x/sqrt2)) with A&S 7.1.26 erf (max abs err 1.5e-7).
__device__ __forceinline__ float gelu_exact(float x) {
    float s = fabsf(x) * 0.70710678118654752f;
    float t = __builtin_amdgcn_rcpf(fmaf(0.3275911f, s, 1.0f));
    float P = t * fmaf(t, fmaf(t, fmaf(t, fmaf(t, 1.061405429f, -1.453152027f),
                                       1.421413741f), -0.284496736f), 0.254829592f);
    float E = __builtin_amdgcn_exp2f(-s * s * 1.4426950408889634f);
    float q = P * E;
    float hxq = 0.5f * x * q;
    return x > 0.f ? x - hxq : hxq;
}

__device__ __forceinline__ void read_row(const float* base, float f[10]) {
    float4 a = *(const float4*)(base);       // 16B-aligned
    float4 b = *(const float4*)(base + 4);
    float2 c = *(const float2*)(base + 8);
    f[0] = a.x; f[1] = a.y; f[2] = a.z; f[3] = a.w;
    f[4] = b.x; f[5] = b.y; f[6] = b.z; f[7] = b.w;
    f[8] = c.x; f[9] = c.y;
}

__device__ __forceinline__ void acc_row(const float f[10], float w0t, float w1t,
                                        float w2t, float acc[8]) {
#pragma unroll
    for (int j = 0; j < 8; j++) {
        acc[j] = fmaf(f[j],     w0t, acc[j]);
        acc[j] = fmaf(f[j + 1], w1t, acc[j]);
        acc[j] = fmaf(f[j + 2], w2t, acc[j]);
    }
}

// One step: dst = gelu(src + depthwise_conv3x3x3(src)), zero padding.
// 512 threads, (b, c, d0..d0+15).
// - 2-slot LDS ping-pong (36 KB), 1 barrier/iter.
// - Full 3-plane register row-cache (Pm1/P0/P1) with unroll-by-3 role rotation:
//   only the FRESH plane (dz+1) is read from LDS each iter (3 rows, was 6).
// - Transposed compute mapping (lanes walk h): row stride 68 floats = +4 banks/row,
//   so each 8-lane LDS phase hits 8 distinct bank-quads -> conflict-free ds_read_b128.
//   Staging (load_g/write_plane) keeps the tid-linear mapping (coalesced, conflict-free).
__global__ __launch_bounds__(512, 4)
void EmergentSpatialPropagation_step(const float* __restrict__ src,
                                     const float* __restrict__ wgt,
                                     float* __restrict__ dst) {
    __shared__ __align__(16) float lds[2 * LPLANE];   // 35904 B

    const int tid = threadIdx.x;
    const int d0  = blockIdx.x * DT;
    const int c   = blockIdx.y;
    const int b   = blockIdx.z;
    const size_t base = ((size_t)(b * Cn + c)) * (size_t)(Dn * PLANE);

    // Zero both slots once; halo cells (rows 0/65, cols 65..67) are never rewritten.
    for (int i = tid; i < 2 * LPLANE; i += 512) lds[i] = 0.0f;

    float wt[27];
#pragma unroll
    for (int k = 0; k < 27; k++) wt[k] = wgt[c * 27 + k];   // block-uniform -> SGPR

    // Transposed compute mapping: consecutive lanes span rows (bank-conflict-free reads).
    const int h  = (tid & 7) | ((tid >> 6) << 3);   // output row 0..63 (wave w -> rows 8w..8w+7)
    const int w0 = ((tid >> 3) & 7) << 3;           // output col group
    const int m  = tid & 15;                        // staging lane role

    // Plane p -> slot parity: d0-1 -> 0, d0 -> 1, d0+1 -> 0, ...
    auto sl = [&](int p) -> float* { return &lds[((p - d0 + 1) & 1) * LPLANE]; };

    // Global plane p -> 2 float4 regs (zeros outside volume). tid-linear, coalesced.
    auto load_g = [&](int p, float4 G[2]) {
        if ((unsigned)p < (unsigned)Dn) {
            const float4* g = (const float4*)(src + base + (size_t)p * PLANE);
            G[0] = g[tid];
            G[1] = g[512 + tid];
        } else {
            G[0] = make_float4(0.f, 0.f, 0.f, 0.f);
            G[1] = make_float4(0.f, 0.f, 0.f, 0.f);
        }
    };

    // Regs -> LDS slot, 16B-aligned writes via shfl repack.
    // Padded cols 4m..4m+3 hold data cols 4m-1..4m+2 = {prev.w, x, y, z}.
    auto write_plane = [&](float* pl, const float4 G[2]) {
#pragma unroll
        for (int i = 0; i < 2; i++) {
            int idx = i * 512 + tid;
            int row = (idx >> 4) + 1;                 // padded row 1..64
            float prev = __shfl_up(G[i].w, 1);
            if (m == 0) prev = 0.f;                   // left zero halo
            float4 Wv = make_float4(prev, G[i].x, G[i].y, G[i].z);
            *(float4*)(pl + row * LSTRIDE + 4 * m) = Wv;
            if (m == 15) pl[row * LSTRIDE + 64] = G[i].w;   // data col 63
        }
    };

    auto read3 = [&](const float* pl, float (&P)[3][10]) {
#pragma unroll
        for (int ky = 0; ky < 3; ky++)
            read_row(pl + (h + ky) * LSTRIDE + w0, P[ky]);
    };

    float PA[3][10], PB[3][10], PC[3][10];

    // ---- Prologue: 3 planes through 2 slots ----
    __syncthreads();   // zeros visible
    {
        float4 Ga[2], Gb[2];
        load_g(d0 - 1, Ga); load_g(d0, Gb);
        write_plane(sl(d0 - 1), Ga); write_plane(sl(d0), Gb);
    }
    __syncthreads();
    read3(sl(d0 - 1), PA);          // Pm1 = plane d0-1
    read3(sl(d0),     PB);          // P0  = plane d0
    {
        float4 Gc[2];
        load_g(d0 + 1, Gc);
        __syncthreads();            // PA reads of slot0 done before overwrite
        write_plane(sl(d0 + 1), Gc);
    }
    __syncthreads();

    auto body = [&](int it, bool last, float (&Pm1)[3][10], float (&P0)[3][10],
                    float (&P1)[3][10]) {
        const int dz = d0 + it;

        // Prefetch plane dz+2 into regs (latency hidden behind FMA block).
        float4 G[2];
        if (!last) load_g(dz + 2, G);

        // Fresh rows of plane dz+1 (written last iter, visible after barrier).
        read3(sl(dz + 1), P1);

        float acc[8];
#pragma unroll
        for (int j = 0; j < 8; j++) acc[j] = 0.f;
#pragma unroll
        for (int ky = 0; ky < 3; ky++)
            acc_row(Pm1[ky], wt[ky * 3 + 0], wt[ky * 3 + 1], wt[ky * 3 + 2], acc);
#pragma unroll
        for (int ky = 0; ky < 3; ky++)
            acc_row(P0[ky], wt[9 + ky * 3 + 0], wt[9 + ky * 3 + 1], wt[9 + ky * 3 + 2], acc);
#pragma unroll
        for (int ky = 0; ky < 3; ky++)
            acc_row(P1[ky], wt[18 + ky * 3 + 0], wt[18 + ky * 3 + 1], wt[18 + ky * 3 + 2], acc);

        float* dptr = dst + base + (size_t)dz * PLANE + h * Wn + w0;
        float4 o0 = make_float4(gelu_exact(P0[1][1] + acc[0]),
                                gelu_exact(P0[1][2] + acc[1]),
                                gelu_exact(P0[1][3] + acc[2]),
                                gelu_exact(P0[1][4] + acc[3]));
        float4 o1 = make_float4(gelu_exact(P0[1][5] + acc[4]),
                                gelu_exact(P0[1][6] + acc[5]),
                                gelu_exact(P0[1][7] + acc[6]),
                                gelu_exact(P0[1][8] + acc[7]));
        *(float4*)(dptr)     = o0;      // 32B-aligned
        *(float4*)(dptr + 4) = o1;

        if (!last) {
            write_plane(sl(dz + 2), G);   // ping-pong slot: read last iter, free now
            __syncthreads();              // single barrier per iteration
        }
    };

    // Role rotation by unroll-by-3: Pm1<-P0<-P1 with zero register copies.
#pragma unroll 1
    for (int bs = 0; bs < DT - 1; bs += 3) {
        body(bs + 0, false, PA, PB, PC);
        body(bs + 1, false, PB, PC, PA);
        body(bs + 2, false, PC, PA, PB);
    }
    body(DT - 1, true, PA, PB, PC);   // 15 % 3 == 0 -> roles back to (PA,PB,PC)
}

extern "C" void kernel_launch(void* const* d_in, const int* in_sizes, int n_in,
                              void* d_out, int out_size, void* d_ws, size_t ws_size,
                              hipStream_t stream) {
    const float* x   = (const float*)d_in[0];
    const float* wgt = (const float*)d_in[1];
    float* out = (float*)d_out;
    float* ws  = (float*)d_ws;

    dim3 grid(Dn / DT, Cn, Bn);   // 4 x 32 x 4 = 512 blocks -> 2/CU resident
    dim3 block(512);

    // 8 steps, ping-pong: in -> ws -> out -> ... -> out
    const float* src = x;
    for (int s = 0; s < 8; s++) {
        float* dst = (s & 1) ? out : ws;
        EmergentSpatialPropagation_step<<<grid, block, 0, stream>>>(src, wgt, dst);
        src = dst;
    }
}

// Round 2
// 758.288 us; speedup vs baseline: 2.1032x; 2.1032x over previous
//
#include <hip/hip_runtime.h>
#include <math.h>

#define Bn 4
#define Cn 32
#define Dn 64
#define Hn 64
#define Wn 64
#define PLANE (Hn * Wn)    // 4096
#define DT 16              // d-planes per block
#define LSTRIDE 68         // padded row stride: 68*4 = 272 B = 17*16 (rows 16B-aligned)
#define LROWS 66           // padded rows 0..65 hold data rows -1..64
#define LPLANE (LROWS * LSTRIDE)   // 4488 floats = 17952 B (multiple of 16)

// Exact-grade GELU: 0.5x(1+erf(x/sqrt2)) with A&S 7.1.26 erf (max abs err 1.5e-7).
__device__ __forceinline__ float gelu_exact(float x) {
    float s = fabsf(x) * 0.70710678118654752f;
    float t = __builtin_amdgcn_rcpf(fmaf(0.3275911f, s, 1.0f));
    float P = t * fmaf(t, fmaf(t, fmaf(t, fmaf(t, 1.061405429f, -1.453152027f),
                                       1.421413741f), -0.284496736f), 0.254829592f);
    float E = __builtin_amdgcn_exp2f(-s * s * 1.4426950408889634f);
    float q = P * E;
    float hxq = 0.5f * x * q;
    return x > 0.f ? x - hxq : hxq;
}

__device__ __forceinline__ void read_row(const float* base, float f[10]) {
    float4 a = *(const float4*)(base);       // 16B-aligned (LSTRIDE*4 = 17*16)
    float4 b = *(const float4*)(base + 4);
    float2 c = *(const float2*)(base + 8);
    f[0] = a.x; f[1] = a.y; f[2] = a.z; f[3] = a.w;
    f[4] = b.x; f[5] = b.y; f[6] = b.z; f[7] = b.w;
    f[8] = c.x; f[9] = c.y;
}

__device__ __forceinline__ void acc_row(const float f[10], float w0t, float w1t,
                                        float w2t, float acc[8]) {
#pragma unroll
    for (int j = 0; j < 8; j++) {
        acc[j] = fmaf(f[j],     w0t, acc[j]);
        acc[j] = fmaf(f[j + 1], w1t, acc[j]);
        acc[j] = fmaf(f[j + 2], w2t, acc[j]);
    }
}

// One step: dst = gelu(src + depthwise_conv3x3x3(src)), zero padding.
// 512 threads, (b, c, d0..d0+15). 4-slot LDS ring, 1 barrier/iter,
// register prefetch of plane dz+2, register row-cache of planes dz, dz+1
// (Round-0 structure: 64 VGPR, no scratch — the 3-plane no-copy cache spilled).
// NEW vs Round 0:
//  - Transposed compute mapping: consecutive lanes walk ROWS (row stride 272 B
//    = 17 chunks of 16 B -> +1 bank-quad mod 8 per lane) so every 8-lane group
//    of a ds_read_b128 hits 8 distinct bank-quads: conflict-free LDS reads.
//    Staging keeps the tid-linear mapping (coalesced, 2-way-free writes).
//  - Vectorized C-store: 2x dwordx4 per thread (wave still covers one
//    contiguous 2 KB row-block, fully coalesced).
__global__ __launch_bounds__(512, 4)
void EmergentSpatialPropagation_step(const float* __restrict__ src,
                                     const float* __restrict__ wgt,
                                     float* __restrict__ dst) {
    __shared__ __align__(16) float lds[4 * LPLANE];   // 71808 B -> 2 blocks/CU

    const int tid = threadIdx.x;
    const int d0  = blockIdx.x * DT;
    const int c   = blockIdx.y;
    const int b   = blockIdx.z;
    const size_t base = ((size_t)(b * Cn + c)) * (size_t)(Dn * PLANE);

    // Zero all 4 slots once; halo cells are never rewritten, stay zero.
    for (int i = tid; i < 4 * LPLANE; i += 512) lds[i] = 0.0f;

    float wt[27];
#pragma unroll
    for (int k = 0; k < 27; k++) wt[k] = wgt[c * 27 + k];   // block-uniform -> SGPR

    // Transposed compute mapping (bank-conflict-free LDS reads).
    const int h  = (tid & 7) | ((tid >> 6) << 3);   // output row: wave w -> rows 8w..8w+7
    const int w0 = ((tid >> 3) & 7) << 3;           // output col group
    const int m  = tid & 15;                        // staging lane role (512 % 16 == 0)

    auto slot = [&](int p) -> float* { return &lds[((p + 1) & 3) * LPLANE]; };

    // Global plane p -> 2 float4 regs (zeros outside volume). tid-linear, coalesced.
    auto load_g = [&](int p, float4 G[2]) {
        if ((unsigned)p < (unsigned)Dn) {
            const float4* g = (const float4*)(src + base + (size_t)p * PLANE);
            G[0] = g[tid];
            G[1] = g[512 + tid];
        } else {
            G[0] = make_float4(0.f, 0.f, 0.f, 0.f);
            G[1] = make_float4(0.f, 0.f, 0.f, 0.f);
        }
    };

    // Regs -> LDS slot, 16B-aligned conflict-free writes via shfl repack.
    // Padded group cols 4m..4m+3 hold data cols 4m-1..4m+2 = {prev.w, x, y, z}.
    auto write_plane = [&](int p, const float4 G[2]) {
        float* pl = slot(p);
#pragma unroll
        for (int i = 0; i < 2; i++) {
            int idx = i * 512 + tid;
            int row = (idx >> 4) + 1;                 // padded row 1..64
            float prev = __shfl_up(G[i].w, 1);
            if (m == 0) prev = 0.f;                   // left zero halo
            float4 Wv = make_float4(prev, G[i].x, G[i].y, G[i].z);
            *(float4*)(pl + row * LSTRIDE + 4 * m) = Wv;
            if (m == 15) pl[row * LSTRIDE + 64] = G[i].w;   // data col 63
        }
    };

    // ---- Prologue: stage planes d0-1, d0, d0+1 ----
    __syncthreads();   // zeros visible before staging writes
    {
        float4 Ga[2], Gb[2], Gc[2];
        load_g(d0 - 1, Ga); load_g(d0, Gb); load_g(d0 + 1, Gc);
        write_plane(d0 - 1, Ga); write_plane(d0, Gb); write_plane(d0 + 1, Gc);
    }
    __syncthreads();

    // Register row-cache: C0 = plane dz rows, C1 = plane dz+1 rows.
    float C0[3][10], C1[3][10];
#pragma unroll
    for (int ky = 0; ky < 3; ky++)
        read_row(slot(d0) + (h + ky) * LSTRIDE + w0, C0[ky]);

    for (int it = 0; it < DT; it++) {
        const int dz = d0 + it;

        // Prefetch plane dz+2 into regs (hidden behind compute).
        float4 G[2];
        if (it < DT - 1) load_g(dz + 2, G);

        // Fresh rows of plane dz+1 (written iter-1, visible after barrier).
#pragma unroll
        for (int ky = 0; ky < 3; ky++)
            read_row(slot(dz + 1) + (h + ky) * LSTRIDE + w0, C1[ky]);

        float acc[8] = {0, 0, 0, 0, 0, 0, 0, 0};

        // Plane dz-1 (last use): read from LDS, consume immediately.
#pragma unroll
        for (int ky = 0; ky < 3; ky++) {
            float T[10];
            read_row(slot(dz - 1) + (h + ky) * LSTRIDE + w0, T);
            acc_row(T, wt[ky * 3 + 0], wt[ky * 3 + 1], wt[ky * 3 + 2], acc);
        }
        // Plane dz (cached).
#pragma unroll
        for (int ky = 0; ky < 3; ky++)
            acc_row(C0[ky], wt[9 + ky * 3 + 0], wt[9 + ky * 3 + 1], wt[9 + ky * 3 + 2], acc);
        // Plane dz+1 (cached).
#pragma unroll
        for (int ky = 0; ky < 3; ky++)
            acc_row(C1[ky], wt[18 + ky * 3 + 0], wt[18 + ky * 3 + 1], wt[18 + ky * 3 + 2], acc);

        float* dptr = dst + base + (size_t)dz * PLANE + h * Wn + w0;
        float4 o0 = make_float4(gelu_exact(C0[1][1] + acc[0]),
                                gelu_exact(C0[1][2] + acc[1]),
                                gelu_exact(C0[1][3] + acc[2]),
                                gelu_exact(C0[1][4] + acc[3]));
        float4 o1 = make_float4(gelu_exact(C0[1][5] + acc[4]),
                                gelu_exact(C0[1][6] + acc[5]),
                                gelu_exact(C0[1][7] + acc[6]),
                                gelu_exact(C0[1][8] + acc[7]));
        *(float4*)(dptr)     = o0;      // w0 multiple of 8 -> 32B-aligned
        *(float4*)(dptr + 4) = o1;

        if (it < DT - 1) {
            write_plane(dz + 2, G);   // slot (dz+3)&3: not read this iter
            __syncthreads();          // single barrier per iteration
        }

        // Rotate cache: plane dz+1 becomes next iter's plane dz.
#pragma unroll
        for (int ky = 0; ky < 3; ky++)
#pragma unroll
            for (int k = 0; k < 10; k++) C0[ky][k] = C1[ky][k];
    }
}

extern "C" void kernel_launch(void* const* d_in, const int* in_sizes, int n_in,
                              void* d_out, int out_size, void* d_ws, size_t ws_size,
                              hipStream_t stream) {
    const float* x   = (const float*)d_in[0];
    const float* wgt = (const float*)d_in[1];
    float* out = (float*)d_out;
    float* ws  = (float*)d_ws;

    dim3 grid(Dn / DT, Cn, Bn);   // 4 x 32 x 4 = 512 blocks -> 2/CU resident
    dim3 block(512);

    // 8 steps, ping-pong: in -> ws -> out -> ... -> out
    const float* src = x;
    for (int s = 0; s < 8; s++) {
        float* dst = (s & 1) ? out : ws;
        EmergentSpatialPropagation_step<<<grid, block, 0, stream>>>(src, wgt, dst);
        src = dst;
    }
}